// Round 1
// baseline (211.866 us; speedup 1.0000x reference)
//
#include <hip/hip_runtime.h>

#define BB 16
#define QQ 1000
#define DDIM 256
#define NH 8
#define NLV 4
#define NPT 4
#define DHD 32
#define NTP 16
#define LTOTAL 5440
#define MQ (BB*QQ)      // 16000
#define MV (BB*LTOTAL)  // 87040

typedef __bf16 bf16x8 __attribute__((ext_vector_type(8)));
typedef float  f32x4  __attribute__((ext_vector_type(4)));

__device__ __forceinline__ unsigned short f2bf(float f) {
  unsigned u = __builtin_bit_cast(unsigned, f);
  u += 0x7fffu + ((u >> 16) & 1u);
  return (unsigned short)(u >> 16);
}
__device__ __forceinline__ float b2f(unsigned short s) {
  unsigned u = ((unsigned)s) << 16;
  return __builtin_bit_cast(float, u);
}

// ---------------- fp32 -> bf16 convert (vectorized float4 -> ushort4) ----------
__global__ __launch_bounds__(256) void cvt_bf16_k(const float* __restrict__ s,
                                                  unsigned short* __restrict__ d,
                                                  int n4) {
  int i = blockIdx.x * 256 + threadIdx.x;
  if (i >= n4) return;
  float4 v = *(const float4*)(s + (size_t)i * 4);
  ushort4 o;
  o.x = f2bf(v.x); o.y = f2bf(v.y); o.z = f2bf(v.z); o.w = f2bf(v.w);
  *(ushort4*)(d + (size_t)i * 4) = o;
}

// ---------------- weight transpose+convert: W[K,N] fp32 -> Wt[N,K] bf16 --------
__global__ __launch_bounds__(256) void wtrans_k(const float* __restrict__ W,
                                                unsigned short* __restrict__ Wt,
                                                int K, int N) {
  int i = blockIdx.x * 256 + threadIdx.x;
  if (i >= K * N) return;
  int k = i / N, n = i - k * N;
  Wt[(size_t)n * K + k] = f2bf(W[i]);
}

__global__ void biascat_k(const float* __restrict__ bo, const float* __restrict__ ba,
                          float* __restrict__ dst) {
  int i = threadIdx.x;
  if (i < 256) dst[i] = bo[i];
  else if (i < 384) dst[i] = ba[i - 256];
}

// ---------------- bf16 MFMA GEMM: C[M,N] = A[M,K=256] @ Wt[N,K]^T + bias -------
// One wave computes a 64x64 output tile directly from global (K=256, weights are
// L1/L2-resident). Block = 4 waves = 4 consecutive tiles (shares A via L1 when
// N=256). All of M,N divide 64 exactly; grids divide 4 exactly.
template <bool OUTBF16>
__global__ __launch_bounds__(256) void gemm_k(const unsigned short* __restrict__ A,
                                              const unsigned short* __restrict__ Wt,
                                              const float* __restrict__ bias,
                                              void* __restrict__ C, int M, int N) {
  const int K = 256;
  int tid  = threadIdx.x;
  int wave = tid >> 6, lane = tid & 63;
  int ntiles = N >> 6;
  int t  = blockIdx.x * 4 + wave;
  int mt = t / ntiles, nt = t - mt * ntiles;
  if (mt >= (M >> 6)) return;
  int r16 = lane & 15, kg = lane >> 4;

  const unsigned short* Ab = A  + (size_t)(mt * 64 + r16) * K + kg * 8;
  const unsigned short* Bb = Wt + (size_t)(nt * 64 + r16) * K + kg * 8;

  f32x4 acc[4][4] = {};

  for (int k0 = 0; k0 < K; k0 += 32) {
    bf16x8 af[4], bfr[4];
#pragma unroll
    for (int mi = 0; mi < 4; mi++)
      af[mi] = *(const bf16x8*)(Ab + (size_t)mi * 16 * K + k0);
#pragma unroll
    for (int ni = 0; ni < 4; ni++)
      bfr[ni] = *(const bf16x8*)(Bb + (size_t)ni * 16 * K + k0);
#pragma unroll
    for (int mi = 0; mi < 4; mi++)
#pragma unroll
      for (int ni = 0; ni < 4; ni++)
        acc[mi][ni] = __builtin_amdgcn_mfma_f32_16x16x32_bf16(af[mi], bfr[ni], acc[mi][ni], 0, 0, 0);
  }

  int row0 = mt * 64 + kg * 4;
  int col0 = nt * 64 + r16;
#pragma unroll
  for (int ni = 0; ni < 4; ni++) {
    int col = col0 + ni * 16;
    float bs = bias[col];
#pragma unroll
    for (int mi = 0; mi < 4; mi++) {
#pragma unroll
      for (int j = 0; j < 4; j++) {
        int row = row0 + mi * 16 + j;
        float v = acc[mi][ni][j] + bs;
        if (OUTBF16) ((unsigned short*)C)[(size_t)row * N + col] = f2bf(v);
        else         ((float*)C)[(size_t)row * N + col] = v;
      }
    }
  }
}

// ---------------- sampling: softmax + bilinear gather-accumulate ----------------
// Block = one (b,q): 8 half-wave groups of 32 lanes, group = head, lane = channel.
// value bf16 [B, LTOTAL, NH, DHD] -> gathers are 64B coalesced per corner.
__global__ __launch_bounds__(256) void sample_k(const float* __restrict__ offattn, // [MQ,384]
                                                const float* __restrict__ refp,    // [B,Q,NLV,2]
                                                const unsigned short* __restrict__ value,
                                                unsigned short* __restrict__ inter) { // [MQ,256] bf16
  int bq = blockIdx.x;
  int h  = threadIdx.x >> 5;
  int c  = threadIdx.x & 31;
  int b  = bq / QQ;

  const float* base = offattn + (size_t)bq * 384;
  const float* ob = base + h * 32;        // offsets: [(lvl*4+pt)*2 + xy]
  const float* ab = base + 256 + h * 16;  // attn logits
  const float* rb = refp + (size_t)bq * 8;

  float lg[16];
  float m = -1e30f;
#pragma unroll
  for (int i = 0; i < 16; i++) { lg[i] = ab[i]; m = fmaxf(m, lg[i]); }
  float s = 0.f;
#pragma unroll
  for (int i = 0; i < 16; i++) { lg[i] = __expf(lg[i] - m); s += lg[i]; }
  float inv = 1.0f / s;

  const unsigned short* vb = value + (size_t)b * (LTOTAL * 256) + h * 32 + c;

  const int   startL[4] = {0, 4096, 5120, 5376};
  const float WLf[4]    = {64.f, 32.f, 16.f, 8.f};
  const float invWL[4]  = {1.f/64.f, 1.f/32.f, 1.f/16.f, 1.f/8.f};

  float acc = 0.f;
#pragma unroll
  for (int lvl = 0; lvl < 4; lvl++) {
    float Wl = WLf[lvl], Hl = WLf[lvl];
    int   Wi = (int)Wl,  Hi = Wi;
    float rx = rb[lvl * 2 + 0], ry = rb[lvl * 2 + 1];
    const unsigned short* vl = vb + (size_t)startL[lvl] * 256;
#pragma unroll
    for (int pt = 0; pt < 4; pt++) {
      int p = lvl * 4 + pt;
      float wa = lg[p] * inv;
      float ox = ob[p * 2 + 0], oy = ob[p * 2 + 1];
      float x = (rx + ox * invWL[lvl]) * Wl - 0.5f;
      float y = (ry + oy * invWL[lvl]) * Hl - 0.5f;
      float x0f = floorf(x), y0f = floorf(y);
      float lx = x - x0f, ly = y - y0f;
      int x0 = (int)x0f, y0 = (int)y0f;
      float wx0 = 1.f - lx, wy0 = 1.f - ly;
#pragma unroll
      for (int cy = 0; cy < 2; cy++) {
        int Y = y0 + cy;
        float wy = cy ? ly : wy0;
        bool vy = (Y >= 0) & (Y < Hi);
        int Yc = Y < 0 ? 0 : (Y > Hi - 1 ? Hi - 1 : Y);
#pragma unroll
        for (int cx = 0; cx < 2; cx++) {
          int X = x0 + cx;
          float wxx = cx ? lx : wx0;
          bool vx = (X >= 0) & (X < Wi);
          int Xc = X < 0 ? 0 : (X > Wi - 1 ? Wi - 1 : X);
          float w = (vx && vy) ? wa * wy * wxx : 0.f;
          float vv = b2f(vl[(size_t)(Yc * Wi + Xc) * 256]);
          acc += w * vv;
        }
      }
    }
  }
  inter[(size_t)bq * 256 + h * 32 + c] = f2bf(acc);
}

extern "C" void kernel_launch(void* const* d_in, const int* in_sizes, int n_in,
                              void* d_out, int out_size, void* d_ws, size_t ws_size,
                              hipStream_t stream) {
  const float* query  = (const float*)d_in[0];
  const float* refp   = (const float*)d_in[1];
  const float* inputf = (const float*)d_in[2];
  const float* Wv   = (const float*)d_in[5];
  const float* bv   = (const float*)d_in[6];
  const float* Wo   = (const float*)d_in[7];
  const float* bo   = (const float*)d_in[8];
  const float* Wa   = (const float*)d_in[9];
  const float* ba   = (const float*)d_in[10];
  const float* Wout = (const float*)d_in[11];
  const float* bout = (const float*)d_in[12];

  char* p = (char*)d_ws;
  auto alloc = [&](size_t bytes) -> char* {
    char* r = p;
    p += (bytes + 255) & ~(size_t)255;
    return r;
  };
  unsigned short* Av    = (unsigned short*)alloc((size_t)MV * 256 * 2);
  unsigned short* Aq    = (unsigned short*)alloc((size_t)MQ * 256 * 2);
  unsigned short* val   = (unsigned short*)alloc((size_t)MV * 256 * 2);
  unsigned short* Wvt   = (unsigned short*)alloc(256 * 256 * 2);
  unsigned short* Wct   = (unsigned short*)alloc(384 * 256 * 2);
  unsigned short* Wot   = (unsigned short*)alloc(256 * 256 * 2);
  float*          bcat  = (float*)alloc(384 * 4);
  float*          offattn = (float*)alloc((size_t)MQ * 384 * 4);
  unsigned short* inter = (unsigned short*)alloc((size_t)MQ * 256 * 2);

  // converts
  cvt_bf16_k<<<(MV * 256 / 4 + 255) / 256, 256, 0, stream>>>(inputf, Av, MV * 256 / 4);
  cvt_bf16_k<<<(MQ * 256 / 4 + 255) / 256, 256, 0, stream>>>(query, Aq, MQ * 256 / 4);
  // weight transposes (tiny)
  wtrans_k<<<(256 * 256 + 255) / 256, 256, 0, stream>>>(Wv, Wvt, 256, 256);
  wtrans_k<<<(256 * 256 + 255) / 256, 256, 0, stream>>>(Wo, Wct, 256, 256);
  wtrans_k<<<(256 * 128 + 255) / 256, 256, 0, stream>>>(Wa, Wct + 256 * 256, 256, 128);
  wtrans_k<<<(256 * 256 + 255) / 256, 256, 0, stream>>>(Wout, Wot, 256, 256);
  biascat_k<<<1, 384, 0, stream>>>(bo, ba, bcat);

  // value = input_flatten @ Wv + bv  -> bf16 [MV,256]
  gemm_k<true><<<(MV / 64) * (256 / 64) / 4, 256, 0, stream>>>(Av, Wvt, bv, val, MV, 256);
  // offattn = query @ [Wo|Wa] + [bo|ba] -> fp32 [MQ,384]
  gemm_k<false><<<(MQ / 64) * (384 / 64) / 4, 256, 0, stream>>>(Aq, Wct, bcat, offattn, MQ, 384);
  // sampling -> inter bf16 [MQ,256]
  sample_k<<<MQ, 256, 0, stream>>>(offattn, refp, val, inter);
  // out = inter @ Wout + bout -> fp32 d_out
  gemm_k<false><<<(MQ / 64) * (256 / 64) / 4, 256, 0, stream>>>(inter, Wot, bout, (float*)d_out, MQ, 256);
}

// Round 2
// 166.207 us; speedup vs baseline: 1.2747x; 1.2747x over previous
//
#include <hip/hip_runtime.h>

#define BB 16
#define QQ 1000
#define DDIM 256
#define NH 8
#define NLV 4
#define NPT 4
#define DHD 32
#define NTP 16
#define LTOTAL 5440
#define MQ (BB*QQ)      // 16000
#define MV (BB*LTOTAL)  // 87040

typedef __bf16 bf16x8 __attribute__((ext_vector_type(8)));
typedef float  f32x4  __attribute__((ext_vector_type(4)));

__device__ __forceinline__ unsigned short f2bf(float f) {
  unsigned u = __builtin_bit_cast(unsigned, f);
  u += 0x7fffu + ((u >> 16) & 1u);
  return (unsigned short)(u >> 16);
}
__device__ __forceinline__ float b2f_lo(unsigned u) {
  return __builtin_bit_cast(float, u << 16);
}
__device__ __forceinline__ float b2f_hi(unsigned u) {
  return __builtin_bit_cast(float, u & 0xffff0000u);
}

// ---------------- prep: all weight transposes (fp32->bf16) + bias concat -------
// W[K,N] row-major fp32 -> Wt[N,K] bf16.  One kernel, 229760 elements.
__global__ __launch_bounds__(256) void prep_k(const float* __restrict__ Wv,
                                              const float* __restrict__ Wo,
                                              const float* __restrict__ Wa,
                                              const float* __restrict__ Wout,
                                              const float* __restrict__ bo,
                                              const float* __restrict__ ba,
                                              unsigned short* __restrict__ Wvt,
                                              unsigned short* __restrict__ Wct,
                                              unsigned short* __restrict__ Wot,
                                              float* __restrict__ bcat) {
  int i = blockIdx.x * 256 + threadIdx.x;
  if (i < 65536) {
    int k = i >> 8, n = i & 255;
    Wvt[n * 256 + k] = f2bf(Wv[i]);
  } else if (i < 131072) {
    int j = i - 65536; int k = j >> 8, n = j & 255;
    Wct[n * 256 + k] = f2bf(Wo[j]);
  } else if (i < 163840) {
    int j = i - 131072; int k = j >> 7, n = j & 127;
    Wct[(256 + n) * 256 + k] = f2bf(Wa[j]);
  } else if (i < 229376) {
    int j = i - 163840; int k = j >> 8, n = j & 255;
    Wot[n * 256 + k] = f2bf(Wout[j]);
  } else if (i < 229760) {
    int j = i - 229376;
    bcat[j] = j < 256 ? bo[j] : ba[j - 256];
  }
}

// ---------------- bf16 MFMA GEMM: C[M,N] = A[M,K=256] @ Wt[N,K]^T + bias -------
// One wave = 64x64 output tile, direct from global (K=256; weights L1/L2-hot).
// AF32: A is fp32, converted in-register (v_cvt_pk_bf16_f32) — fuses the cvt pass.
template <bool AF32, bool OUTBF16>
__global__ __launch_bounds__(256) void gemm_k(const void* __restrict__ Av,
                                              const unsigned short* __restrict__ Wt,
                                              const float* __restrict__ bias,
                                              void* __restrict__ C, int M, int N) {
  const int K = 256;
  int tid  = threadIdx.x;
  int wave = tid >> 6, lane = tid & 63;
  int ntiles = N >> 6;
  int t  = blockIdx.x * 4 + wave;
  int mt = t / ntiles, nt = t - mt * ntiles;
  if (mt >= (M >> 6)) return;
  int r16 = lane & 15, kg = lane >> 4;

  const unsigned short* Bb = Wt + (size_t)(nt * 64 + r16) * K + kg * 8;

  f32x4 acc[4][4] = {};

  for (int k0 = 0; k0 < K; k0 += 32) {
    bf16x8 af[4], bfr[4];
    if (AF32) {
      const float* Ab = (const float*)Av + (size_t)(mt * 64 + r16) * K + kg * 8;
#pragma unroll
      for (int mi = 0; mi < 4; mi++) {
        const float* ap = Ab + (size_t)mi * 16 * K + k0;
        float4 lo = *(const float4*)ap;
        float4 hi = *(const float4*)(ap + 4);
        bf16x8 r;
        r[0] = (__bf16)lo.x; r[1] = (__bf16)lo.y; r[2] = (__bf16)lo.z; r[3] = (__bf16)lo.w;
        r[4] = (__bf16)hi.x; r[5] = (__bf16)hi.y; r[6] = (__bf16)hi.z; r[7] = (__bf16)hi.w;
        af[mi] = r;
      }
    } else {
      const unsigned short* Ab = (const unsigned short*)Av + (size_t)(mt * 64 + r16) * K + kg * 8;
#pragma unroll
      for (int mi = 0; mi < 4; mi++)
        af[mi] = *(const bf16x8*)(Ab + (size_t)mi * 16 * K + k0);
    }
#pragma unroll
    for (int ni = 0; ni < 4; ni++)
      bfr[ni] = *(const bf16x8*)(Bb + (size_t)ni * 16 * K + k0);
#pragma unroll
    for (int mi = 0; mi < 4; mi++)
#pragma unroll
      for (int ni = 0; ni < 4; ni++)
        acc[mi][ni] = __builtin_amdgcn_mfma_f32_16x16x32_bf16(af[mi], bfr[ni], acc[mi][ni], 0, 0, 0);
  }

  int row0 = mt * 64 + kg * 4;
  int col0 = nt * 64 + r16;
#pragma unroll
  for (int ni = 0; ni < 4; ni++) {
    int col = col0 + ni * 16;
    float bs = bias[col];
#pragma unroll
    for (int mi = 0; mi < 4; mi++) {
#pragma unroll
      for (int j = 0; j < 4; j++) {
        int row = row0 + mi * 16 + j;
        float v = acc[mi][ni][j] + bs;
        if (OUTBF16) ((unsigned short*)C)[(size_t)row * N + col] = f2bf(v);
        else         ((float*)C)[(size_t)row * N + col] = v;
      }
    }
  }
}

// ---------------- sampling: softmax + bilinear gather-accumulate ----------------
// 32 lanes per (b,q): lane = (c-octet 0..3, head 0..7); each lane owns 8 channels
// and gathers ushort8 (16B) per corner -> per-point/per-corner arithmetic is
// amortized 8x vs lane-per-channel. Block = 256 threads = 8 queries.
__global__ __launch_bounds__(256) void sample_k(const float* __restrict__ offattn, // [MQ,384] f32
                                                const float* __restrict__ refp,    // [B,Q,4,2]
                                                const unsigned short* __restrict__ value, // [MV,256] bf16
                                                unsigned short* __restrict__ inter) {     // [MQ,256] bf16
  int t  = blockIdx.x * 256 + threadIdx.x;
  int bq = t >> 5;
  int h  = (t >> 2) & 7;
  int c0 = (t & 3) << 3;
  int b  = bq / QQ;

  const float* base = offattn + (size_t)bq * 384;

  float off[32];
  const float4* ob4 = (const float4*)(base + h * 32);
#pragma unroll
  for (int i = 0; i < 8; i++) {
    float4 v = ob4[i];
    off[4*i] = v.x; off[4*i+1] = v.y; off[4*i+2] = v.z; off[4*i+3] = v.w;
  }
  float lg[16];
  const float4* ab4 = (const float4*)(base + 256 + h * 16);
#pragma unroll
  for (int i = 0; i < 4; i++) {
    float4 v = ab4[i];
    lg[4*i] = v.x; lg[4*i+1] = v.y; lg[4*i+2] = v.z; lg[4*i+3] = v.w;
  }
  float m = -1e30f;
#pragma unroll
  for (int i = 0; i < 16; i++) m = fmaxf(m, lg[i]);
  float s = 0.f;
#pragma unroll
  for (int i = 0; i < 16; i++) { lg[i] = __expf(lg[i] - m); s += lg[i]; }
  float inv = 1.0f / s;

  float4 r01 = ((const float4*)(refp + (size_t)bq * 8))[0];
  float4 r23 = ((const float4*)(refp + (size_t)bq * 8))[1];
  float rxs[4] = {r01.x, r01.z, r23.x, r23.z};
  float rys[4] = {r01.y, r01.w, r23.y, r23.w};

  const unsigned short* vb = value + (size_t)b * (LTOTAL * 256) + h * 32 + c0;
  const int startL[4] = {0, 4096, 5120, 5376};

  float acc[8] = {};
#pragma unroll
  for (int lvl = 0; lvl < 4; lvl++) {
    int   Wi = 64 >> lvl;
    float Wf = (float)Wi;
    float px = rxs[lvl] * Wf - 0.5f;
    float py = rys[lvl] * Wf - 0.5f;
    const unsigned short* vl = vb + (size_t)startL[lvl] * 256;
#pragma unroll
    for (int pt = 0; pt < 4; pt++) {
      int p = lvl * 4 + pt;
      float wa = lg[p] * inv;
      float x = px + off[2*p];
      float y = py + off[2*p + 1];
      float xf = floorf(x), yf = floorf(y);
      float lx = x - xf, ly = y - yf;
      int x0 = (int)xf, y0 = (int)yf;
      float wx[2] = {1.f - lx, lx};
      float wy[2] = {1.f - ly, ly};
#pragma unroll
      for (int cy = 0; cy < 2; cy++) {
        int Y = y0 + cy;
        bool vy = (unsigned)Y < (unsigned)Wi;
        int Yc = min(max(Y, 0), Wi - 1);
#pragma unroll
        for (int cx = 0; cx < 2; cx++) {
          int X = x0 + cx;
          bool vx = (unsigned)X < (unsigned)Wi;
          int Xc = min(max(X, 0), Wi - 1);
          float w = (vx && vy) ? wa * wy[cy] * wx[cx] : 0.f;
          uint4 raw = *(const uint4*)(vl + (size_t)(Yc * Wi + Xc) * 256);
          acc[0] += w * b2f_lo(raw.x); acc[1] += w * b2f_hi(raw.x);
          acc[2] += w * b2f_lo(raw.y); acc[3] += w * b2f_hi(raw.y);
          acc[4] += w * b2f_lo(raw.z); acc[5] += w * b2f_hi(raw.z);
          acc[6] += w * b2f_lo(raw.w); acc[7] += w * b2f_hi(raw.w);
        }
      }
    }
  }

  unsigned o0 = f2bf(acc[0]) | ((unsigned)f2bf(acc[1]) << 16);
  unsigned o1 = f2bf(acc[2]) | ((unsigned)f2bf(acc[3]) << 16);
  unsigned o2 = f2bf(acc[4]) | ((unsigned)f2bf(acc[5]) << 16);
  unsigned o3 = f2bf(acc[6]) | ((unsigned)f2bf(acc[7]) << 16);
  uint4 st = {o0, o1, o2, o3};
  *(uint4*)(inter + (size_t)bq * 256 + h * 32 + c0) = st;
}

extern "C" void kernel_launch(void* const* d_in, const int* in_sizes, int n_in,
                              void* d_out, int out_size, void* d_ws, size_t ws_size,
                              hipStream_t stream) {
  const float* query  = (const float*)d_in[0];
  const float* refp   = (const float*)d_in[1];
  const float* inputf = (const float*)d_in[2];
  const float* Wv   = (const float*)d_in[5];
  const float* bv   = (const float*)d_in[6];
  const float* Wo   = (const float*)d_in[7];
  const float* bo   = (const float*)d_in[8];
  const float* Wa   = (const float*)d_in[9];
  const float* ba   = (const float*)d_in[10];
  const float* Wout = (const float*)d_in[11];
  const float* bout = (const float*)d_in[12];

  char* p = (char*)d_ws;
  auto alloc = [&](size_t bytes) -> char* {
    char* r = p;
    p += (bytes + 255) & ~(size_t)255;
    return r;
  };
  unsigned short* val   = (unsigned short*)alloc((size_t)MV * 256 * 2);
  unsigned short* Wvt   = (unsigned short*)alloc(256 * 256 * 2);
  unsigned short* Wct   = (unsigned short*)alloc(384 * 256 * 2);
  unsigned short* Wot   = (unsigned short*)alloc(256 * 256 * 2);
  float*          bcat  = (float*)alloc(384 * 4);
  float*          offattn = (float*)alloc((size_t)MQ * 384 * 4);
  unsigned short* inter = (unsigned short*)alloc((size_t)MQ * 256 * 2);

  // weights transpose+cvt + bias concat (one kernel)
  prep_k<<<898, 256, 0, stream>>>(Wv, Wo, Wa, Wout, bo, ba, Wvt, Wct, Wot, bcat);

  // value = input_flatten @ Wv + bv  (fp32 A fused-convert) -> bf16 [MV,256]
  gemm_k<true, true><<<(MV / 64) * (256 / 64) / 4, 256, 0, stream>>>(
      (const void*)inputf, Wvt, bv, val, MV, 256);
  // offattn = query @ [Wo|Wa] + [bo|ba] (fp32 A fused-convert) -> fp32 [MQ,384]
  gemm_k<true, false><<<(MQ / 64) * (384 / 64) / 4, 256, 0, stream>>>(
      (const void*)query, Wct, bcat, offattn, MQ, 384);
  // sampling -> inter bf16 [MQ,256]
  sample_k<<<MQ * 32 / 256, 256, 0, stream>>>(offattn, refp, val, inter);
  // out = inter @ Wout + bout -> fp32 d_out
  gemm_k<false, false><<<(MQ / 64) * (256 / 64) / 4, 256, 0, stream>>>(
      (const void*)inter, Wot, bout, (float*)d_out, MQ, 256);
}

// Round 3
// 117.070 us; speedup vs baseline: 1.8097x; 1.4197x over previous
//
#include <hip/hip_runtime.h>

#define BB 16
#define QQ 1000
#define NH 8
#define LTOTAL 5440
#define MQ (BB*QQ)      // 16000
#define MV (BB*LTOTAL)  // 87040

typedef __bf16 bf16x8 __attribute__((ext_vector_type(8)));
typedef float  f32x4  __attribute__((ext_vector_type(4)));

__device__ __forceinline__ unsigned short f2bf(float f) {
  unsigned u = __builtin_bit_cast(unsigned, f);
  u += 0x7fffu + ((u >> 16) & 1u);
  return (unsigned short)(u >> 16);
}
__device__ __forceinline__ float b2f_lo(unsigned u) {
  return __builtin_bit_cast(float, u << 16);
}
__device__ __forceinline__ float b2f_hi(unsigned u) {
  return __builtin_bit_cast(float, u & 0xffff0000u);
}

__device__ __forceinline__ void gload16(const void* g, void* l) {
  __builtin_amdgcn_global_load_lds(
      (const __attribute__((address_space(1))) unsigned int*)g,
      (__attribute__((address_space(3))) unsigned int*)l, 16, 0, 0);
}

// ---------------- prep: all weight transposes (fp32->bf16) + bias concat -------
__global__ __launch_bounds__(256) void prep_k(const float* __restrict__ Wv,
                                              const float* __restrict__ Wo,
                                              const float* __restrict__ Wa,
                                              const float* __restrict__ Wout,
                                              const float* __restrict__ bo,
                                              const float* __restrict__ ba,
                                              unsigned short* __restrict__ Wvt,
                                              unsigned short* __restrict__ Wct,
                                              unsigned short* __restrict__ Wot,
                                              float* __restrict__ bcat) {
  int i = blockIdx.x * 256 + threadIdx.x;
  if (i < 65536) {
    int k = i >> 8, n = i & 255;
    Wvt[n * 256 + k] = f2bf(Wv[i]);
  } else if (i < 131072) {
    int j = i - 65536; int k = j >> 8, n = j & 255;
    Wct[n * 256 + k] = f2bf(Wo[j]);
  } else if (i < 163840) {
    int j = i - 131072; int k = j >> 7, n = j & 127;
    Wct[(256 + n) * 256 + k] = f2bf(Wa[j]);
  } else if (i < 229376) {
    int j = i - 163840; int k = j >> 8, n = j & 255;
    Wot[n * 256 + k] = f2bf(Wout[j]);
  } else if (i < 229760) {
    int j = i - 229376;
    bcat[j] = j < 256 ? bo[j] : ba[j - 256];
  }
}

// ---------------- LDS-staged MFMA GEMM: C[M,N] = A[M,256] @ Wt[N,256]^T + bias --
// 128x128 tile, 4 waves (2x2, each 64x64), BK=32, double-buffered LDS staged via
// global_load_lds width=16 with counted vmcnt (stage t+1 issued before compute t,
// never drained to 0 mid-loop). LDS dest linear, XOR-swizzle applied to the
// GLOBAL source address and the ds_read address (rule #21: same involution).
template <bool AF32, bool OUTBF16>
__global__ __launch_bounds__(256) void gemm_lds_k(const void* __restrict__ Av,
                                                  const unsigned short* __restrict__ Wt,
                                                  const float* __restrict__ bias,
                                                  void* __restrict__ C, int M, int N) {
  constexpr int K = 256;
  constexpr int NT = 8;                        // K / 32
  constexpr int ABUF = AF32 ? 16384 : 8192;    // one A stage
  __shared__ char lds[(AF32 ? 32768 : 16384) + 16384];
  char* As = lds;
  char* Bs = lds + 2 * ABUF;

  int tid  = threadIdx.x;
  int wave = tid >> 6, lane = tid & 63;
  int ntiles = N >> 7;
  int bid = blockIdx.x;
  int mt = bid / ntiles, nt = bid - mt * ntiles;
  int r16 = lane & 15, kg = lane >> 4;
  int wm = wave >> 1, wn = wave & 1;

  f32x4 acc[4][4] = {};

  auto stage = [&](int t) {
    int k0 = t * 32;
    char* Ad = As + (t & 1) * ABUF;
    char* Bd = Bs + (t & 1) * 8192;
    if (AF32) {
#pragma unroll
      for (int j = 0; j < 4; j++) {
        int f = (j * 4 + wave) * 64 + lane;     // granule 0..1023
        int row = f >> 3, u = f & 7;            // 8x16B per 128B row
        const float* src = (const float*)Av +
            (size_t)(mt * 128 + row) * K + k0 + ((u ^ (row & 7)) << 2);
        gload16(src, Ad + (size_t)f * 16);
      }
    } else {
#pragma unroll
      for (int j = 0; j < 2; j++) {
        int f = (j * 4 + wave) * 64 + lane;     // granule 0..511
        int row = f >> 2, u = f & 3;            // 4x16B per 64B row
        const unsigned short* src = (const unsigned short*)Av +
            (size_t)(mt * 128 + row) * K + k0 + ((u ^ (row & 3)) << 3);
        gload16(src, Ad + (size_t)f * 16);
      }
    }
#pragma unroll
    for (int j = 0; j < 2; j++) {
      int f = (j * 4 + wave) * 64 + lane;
      int row = f >> 2, u = f & 3;
      const unsigned short* src = Wt +
          (size_t)(nt * 128 + row) * K + k0 + ((u ^ (row & 3)) << 3);
      gload16(src, Bd + (size_t)f * 16);
    }
  };

  auto computeStep = [&](int b) {
    const char* Ad = As + b * ABUF;
    const char* Bd = Bs + b * 8192;
    bf16x8 af[4], bfr[4];
    if (AF32) {
#pragma unroll
      for (int mi = 0; mi < 4; mi++) {
        int row = wm * 64 + mi * 16 + r16;
        int sw = row & 7;
        f32x4 lo = *(const f32x4*)(Ad + row * 128 + ((((kg << 1))     ^ sw) << 4));
        f32x4 hi = *(const f32x4*)(Ad + row * 128 + ((((kg << 1) | 1) ^ sw) << 4));
        bf16x8 r;
        r[0] = (__bf16)lo[0]; r[1] = (__bf16)lo[1]; r[2] = (__bf16)lo[2]; r[3] = (__bf16)lo[3];
        r[4] = (__bf16)hi[0]; r[5] = (__bf16)hi[1]; r[6] = (__bf16)hi[2]; r[7] = (__bf16)hi[3];
        af[mi] = r;
      }
    } else {
#pragma unroll
      for (int mi = 0; mi < 4; mi++) {
        int row = wm * 64 + mi * 16 + r16;
        af[mi] = *(const bf16x8*)(Ad + row * 64 + ((kg ^ (row & 3)) << 4));
      }
    }
#pragma unroll
    for (int ni = 0; ni < 4; ni++) {
      int row = wn * 64 + ni * 16 + r16;
      bfr[ni] = *(const bf16x8*)(Bd + row * 64 + ((kg ^ (row & 3)) << 4));
    }
#pragma unroll
    for (int mi = 0; mi < 4; mi++)
#pragma unroll
      for (int ni = 0; ni < 4; ni++)
        acc[mi][ni] = __builtin_amdgcn_mfma_f32_16x16x32_bf16(af[mi], bfr[ni], acc[mi][ni], 0, 0, 0);
  };

  stage(0);
  for (int t = 0; t < NT - 1; ++t) {
    stage(t + 1);
    if (AF32) asm volatile("s_waitcnt vmcnt(6)" ::: "memory");
    else      asm volatile("s_waitcnt vmcnt(4)" ::: "memory");
    __syncthreads();
    computeStep(t & 1);
    __syncthreads();
  }
  asm volatile("s_waitcnt vmcnt(0)" ::: "memory");
  __syncthreads();
  computeStep((NT - 1) & 1);

  int row0 = mt * 128 + wm * 64 + kg * 4;
  int col0 = nt * 128 + wn * 64 + r16;
#pragma unroll
  for (int ni = 0; ni < 4; ni++) {
    int col = col0 + ni * 16;
    float bs = bias[col];
#pragma unroll
    for (int mi = 0; mi < 4; mi++) {
#pragma unroll
      for (int j = 0; j < 4; j++) {
        int row = row0 + mi * 16 + j;
        float v = acc[mi][ni][j] + bs;
        if (OUTBF16) ((unsigned short*)C)[(size_t)row * N + col] = f2bf(v);
        else         ((float*)C)[(size_t)row * N + col] = v;
      }
    }
  }
}

// ---------------- sampling: softmax + bilinear gather-accumulate ----------------
// 32 lanes per (b,q): lane = (c-octet 0..3, head 0..7); each lane owns 8 channels
// and gathers ushort8 (16B) per corner. Block = 256 threads = 8 queries.
__global__ __launch_bounds__(256) void sample_k(const float* __restrict__ offattn, // [MQ,384] f32
                                                const float* __restrict__ refp,    // [B,Q,4,2]
                                                const unsigned short* __restrict__ value, // [MV,256] bf16
                                                unsigned short* __restrict__ inter) {     // [MQ,256] bf16
  int t  = blockIdx.x * 256 + threadIdx.x;
  int bq = t >> 5;
  int h  = (t >> 2) & 7;
  int c0 = (t & 3) << 3;
  int b  = bq / QQ;

  const float* base = offattn + (size_t)bq * 384;

  float off[32];
  const float4* ob4 = (const float4*)(base + h * 32);
#pragma unroll
  for (int i = 0; i < 8; i++) {
    float4 v = ob4[i];
    off[4*i] = v.x; off[4*i+1] = v.y; off[4*i+2] = v.z; off[4*i+3] = v.w;
  }
  float lg[16];
  const float4* ab4 = (const float4*)(base + 256 + h * 16);
#pragma unroll
  for (int i = 0; i < 4; i++) {
    float4 v = ab4[i];
    lg[4*i] = v.x; lg[4*i+1] = v.y; lg[4*i+2] = v.z; lg[4*i+3] = v.w;
  }
  float m = -1e30f;
#pragma unroll
  for (int i = 0; i < 16; i++) m = fmaxf(m, lg[i]);
  float s = 0.f;
#pragma unroll
  for (int i = 0; i < 16; i++) { lg[i] = __expf(lg[i] - m); s += lg[i]; }
  float inv = 1.0f / s;

  float4 r01 = ((const float4*)(refp + (size_t)bq * 8))[0];
  float4 r23 = ((const float4*)(refp + (size_t)bq * 8))[1];
  float rxs[4] = {r01.x, r01.z, r23.x, r23.z};
  float rys[4] = {r01.y, r01.w, r23.y, r23.w};

  const unsigned short* vb = value + (size_t)b * (LTOTAL * 256) + h * 32 + c0;
  const int startL[4] = {0, 4096, 5120, 5376};

  float acc[8] = {};
#pragma unroll
  for (int lvl = 0; lvl < 4; lvl++) {
    int   Wi = 64 >> lvl;
    float Wf = (float)Wi;
    float px = rxs[lvl] * Wf - 0.5f;
    float py = rys[lvl] * Wf - 0.5f;
    const unsigned short* vl = vb + (size_t)startL[lvl] * 256;
#pragma unroll
    for (int pt = 0; pt < 4; pt++) {
      int p = lvl * 4 + pt;
      float wa = lg[p] * inv;
      float x = px + off[2*p];
      float y = py + off[2*p + 1];
      float xf = floorf(x), yf = floorf(y);
      float lx = x - xf, ly = y - yf;
      int x0 = (int)xf, y0 = (int)yf;
      float wx[2] = {1.f - lx, lx};
      float wy[2] = {1.f - ly, ly};
#pragma unroll
      for (int cy = 0; cy < 2; cy++) {
        int Y = y0 + cy;
        bool vy = (unsigned)Y < (unsigned)Wi;
        int Yc = min(max(Y, 0), Wi - 1);
#pragma unroll
        for (int cx = 0; cx < 2; cx++) {
          int X = x0 + cx;
          bool vx = (unsigned)X < (unsigned)Wi;
          int Xc = min(max(X, 0), Wi - 1);
          float w = (vx && vy) ? wa * wy[cy] * wx[cx] : 0.f;
          uint4 raw = *(const uint4*)(vl + (size_t)(Yc * Wi + Xc) * 256);
          acc[0] += w * b2f_lo(raw.x); acc[1] += w * b2f_hi(raw.x);
          acc[2] += w * b2f_lo(raw.y); acc[3] += w * b2f_hi(raw.y);
          acc[4] += w * b2f_lo(raw.z); acc[5] += w * b2f_hi(raw.z);
          acc[6] += w * b2f_lo(raw.w); acc[7] += w * b2f_hi(raw.w);
        }
      }
    }
  }

  unsigned o0 = f2bf(acc[0]) | ((unsigned)f2bf(acc[1]) << 16);
  unsigned o1 = f2bf(acc[2]) | ((unsigned)f2bf(acc[3]) << 16);
  unsigned o2 = f2bf(acc[4]) | ((unsigned)f2bf(acc[5]) << 16);
  unsigned o3 = f2bf(acc[6]) | ((unsigned)f2bf(acc[7]) << 16);
  uint4 st = {o0, o1, o2, o3};
  *(uint4*)(inter + (size_t)bq * 256 + h * 32 + c0) = st;
}

extern "C" void kernel_launch(void* const* d_in, const int* in_sizes, int n_in,
                              void* d_out, int out_size, void* d_ws, size_t ws_size,
                              hipStream_t stream) {
  const float* query  = (const float*)d_in[0];
  const float* refp   = (const float*)d_in[1];
  const float* inputf = (const float*)d_in[2];
  const float* Wv   = (const float*)d_in[5];
  const float* bv   = (const float*)d_in[6];
  const float* Wo   = (const float*)d_in[7];
  const float* bo   = (const float*)d_in[8];
  const float* Wa   = (const float*)d_in[9];
  const float* ba   = (const float*)d_in[10];
  const float* Wout = (const float*)d_in[11];
  const float* bout = (const float*)d_in[12];

  char* p = (char*)d_ws;
  auto alloc = [&](size_t bytes) -> char* {
    char* r = p;
    p += (bytes + 255) & ~(size_t)255;
    return r;
  };
  unsigned short* val   = (unsigned short*)alloc((size_t)MV * 256 * 2);
  unsigned short* Wvt   = (unsigned short*)alloc(256 * 256 * 2);
  unsigned short* Wct   = (unsigned short*)alloc(384 * 256 * 2);
  unsigned short* Wot   = (unsigned short*)alloc(256 * 256 * 2);
  float*          bcat  = (float*)alloc(384 * 4);
  float*          offattn = (float*)alloc((size_t)MQ * 384 * 4);
  unsigned short* inter = (unsigned short*)alloc((size_t)MQ * 256 * 2);

  prep_k<<<898, 256, 0, stream>>>(Wv, Wo, Wa, Wout, bo, ba, Wvt, Wct, Wot, bcat);

  // value = input_flatten @ Wv + bv (fp32 A, fused cvt) -> bf16 [MV,256]
  gemm_lds_k<true, true><<<(MV / 128) * (256 / 128), 256, 0, stream>>>(
      (const void*)inputf, Wvt, bv, val, MV, 256);
  // offattn = query @ [Wo|Wa] + [bo|ba] -> fp32 [MQ,384]
  gemm_lds_k<true, false><<<(MQ / 128) * (384 / 128), 256, 0, stream>>>(
      (const void*)query, Wct, bcat, offattn, MQ, 384);
  // sampling -> inter bf16 [MQ,256]
  sample_k<<<MQ * 32 / 256, 256, 0, stream>>>(offattn, refp, val, inter);
  // out = inter @ Wout + bout -> fp32 d_out
  gemm_lds_k<false, false><<<(MQ / 128) * (256 / 128), 256, 0, stream>>>(
      (const void*)inter, Wot, bout, (float*)d_out, MQ, 256);
}